// Round 2
// baseline (680.747 us; speedup 1.0000x reference)
//
#include <hip/hip_runtime.h>
#include <hip/hip_bf16.h>
#include <math.h>

typedef __bf16 bf16;
typedef bf16 bf16x8 __attribute__((ext_vector_type(8)));
typedef bf16 bf16x4 __attribute__((ext_vector_type(4)));
typedef float f32x4 __attribute__((ext_vector_type(4)));

#define NFRM 16
#define SEQ  1472
#define TOK  (NFRM * SEQ)   /* 23552 */
#define DIM_ 1024
#define NH_  16
#define HD_  64
#define KROW 1032           /* LDS row stride (bf16) for k/v: 1024 + 8 pad */

// ---------------------------------------------------------------------------
// async global->LDS, 16B per lane. LDS dest must be wave-uniform base.
// ---------------------------------------------------------------------------
__device__ __forceinline__ void load_lds_16B(const void* g, void* l) {
  __builtin_amdgcn_global_load_lds(
      (const __attribute__((address_space(1))) unsigned int*)g,
      (__attribute__((address_space(3))) unsigned int*)l,
      16, 0, 0);
}

// ---------------------------------------------------------------------------
// fp32 -> bf16 conversion (8 elems/thread, 16B stores). n % 2048 == 0.
// ---------------------------------------------------------------------------
__global__ __launch_bounds__(256) void cvt_bf16(const float* __restrict__ s,
                                                bf16* __restrict__ d, int n) {
  size_t i = ((size_t)blockIdx.x * 256 + threadIdx.x) * 8;
  if (i >= (size_t)n) return;
  f32x4 a = *(const f32x4*)(s + i);
  f32x4 b = *(const f32x4*)(s + i + 4);
  bf16x8 o;
  o[0] = (bf16)a[0]; o[1] = (bf16)a[1]; o[2] = (bf16)a[2]; o[3] = (bf16)a[3];
  o[4] = (bf16)b[0]; o[5] = (bf16)b[1]; o[6] = (bf16)b[2]; o[7] = (bf16)b[3];
  *(bf16x8*)(d + i) = o;
}

// four 1Mx-elem weight tensors in one launch (blockIdx.y selects tensor)
__global__ __launch_bounds__(256) void cvt_w4(
    const float* __restrict__ w0, const float* __restrict__ w1,
    const float* __restrict__ w2, const float* __restrict__ w3,
    bf16* __restrict__ d0, bf16* __restrict__ d1,
    bf16* __restrict__ d2, bf16* __restrict__ d3) {
  const int z = blockIdx.y;
  const float* s = (z == 0) ? w0 : (z == 1) ? w1 : (z == 2) ? w2 : w3;
  bf16* d       = (z == 0) ? d0 : (z == 1) ? d1 : (z == 2) ? d2 : d3;
  size_t i = ((size_t)blockIdx.x * 256 + threadIdx.x) * 8;
  f32x4 a = *(const f32x4*)(s + i);
  f32x4 b = *(const f32x4*)(s + i + 4);
  bf16x8 o;
  o[0] = (bf16)a[0]; o[1] = (bf16)a[1]; o[2] = (bf16)a[2]; o[3] = (bf16)a[3];
  o[4] = (bf16)b[0]; o[5] = (bf16)b[1]; o[6] = (bf16)b[2]; o[7] = (bf16)b[3];
  *(bf16x8*)(d + i) = o;
}

// ---------------------------------------------------------------------------
// m97-structure GEMM: C[M][1024] = A[M][1024] @ B[1024][1024]^T + bias
// ---------------------------------------------------------------------------
template <typename OutT>
__device__ __forceinline__ void gemm_body(const bf16* __restrict__ A,
                                          const bf16* __restrict__ B,
                                          const float* __restrict__ bias,
                                          OutT* __restrict__ C,
                                          bf16* As, bf16* Bs) {
  const int tid  = threadIdx.x;
  const int wave = tid >> 6;
  const int lane = tid & 63;
  const size_t am0 = (size_t)blockIdx.x * 128;
  const size_t bn0 = (size_t)blockIdx.y * 128;

  f32x4 acc[4][4];
#pragma unroll
  for (int i = 0; i < 4; ++i)
#pragma unroll
    for (int j = 0; j < 4; ++j) {
      f32x4 z = {0.f, 0.f, 0.f, 0.f};
      acc[i][j] = z;
    }

  const int wm   = (wave >> 1) * 64;
  const int wn   = (wave & 1) * 64;
  const int frow = lane & 15;
  const int fko  = (lane >> 4) * 8;

  for (int k0 = 0; k0 < DIM_; k0 += 32) {
#pragma unroll
    for (int it = 0; it < 2; ++it) {
      const int cb  = it * 256 + wave * 64;
      const int c   = cb + lane;
      const int row = c >> 2;
      const int kc  = (c & 3) * 8;
      load_lds_16B(A + (am0 + row) * DIM_ + k0 + kc, As + cb * 8);
      load_lds_16B(B + (bn0 + row) * DIM_ + k0 + kc, Bs + cb * 8);
    }
    __syncthreads();
    bf16x8 af[4], bfv[4];
#pragma unroll
    for (int i = 0; i < 4; ++i)
      af[i] = *(const bf16x8*)(As + (wm + i * 16 + frow) * 32 + fko);
#pragma unroll
    for (int j = 0; j < 4; ++j)
      bfv[j] = *(const bf16x8*)(Bs + (wn + j * 16 + frow) * 32 + fko);
#pragma unroll
    for (int i = 0; i < 4; ++i)
#pragma unroll
      for (int j = 0; j < 4; ++j)
        acc[i][j] = __builtin_amdgcn_mfma_f32_16x16x32_bf16(af[i], bfv[j],
                                                            acc[i][j], 0, 0, 0);
    __syncthreads();
  }

  const int cl = lane & 15;
  const int rq = (lane >> 4) * 4;
#pragma unroll
  for (int i = 0; i < 4; ++i)
#pragma unroll
    for (int j = 0; j < 4; ++j) {
      const int nc   = (int)bn0 + wn + j * 16 + cl;
      const float bb = bias[nc];
#pragma unroll
      for (int r = 0; r < 4; ++r) {
        const size_t mr = am0 + wm + i * 16 + rq + r;
        C[mr * DIM_ + nc] = (OutT)(acc[i][j][r] + bb);
      }
    }
}

__global__ __launch_bounds__(256) void gemm_qkv(
    const bf16* __restrict__ A,
    const bf16* __restrict__ Bq, const bf16* __restrict__ Bk,
    const bf16* __restrict__ Bv,
    const float* __restrict__ bq, const float* __restrict__ bk,
    const float* __restrict__ bv,
    bf16* __restrict__ Cq, bf16* __restrict__ Ck, bf16* __restrict__ Cv) {
  __shared__ __align__(16) bf16 As[128 * 32];
  __shared__ __align__(16) bf16 Bs[128 * 32];
  const int z = blockIdx.z;
  const bf16* B    = (z == 0) ? Bq : (z == 1) ? Bk : Bv;
  const float* bia = (z == 0) ? bq : (z == 1) ? bk : bv;
  bf16* C          = (z == 0) ? Cq : (z == 1) ? Ck : Cv;
  gemm_body<bf16>(A, B, bia, C, As, Bs);
}

__global__ __launch_bounds__(256) void gemm_out(
    const bf16* __restrict__ A, const bf16* __restrict__ B,
    const float* __restrict__ bias, float* __restrict__ C) {
  __shared__ __align__(16) bf16 As[128 * 32];
  __shared__ __align__(16) bf16 Bs[128 * 32];
  gemm_body<float>(A, B, bias, C, As, Bs);
}

// ---------------------------------------------------------------------------
// In-place RMSNorm + RoPE. Wave per row, 4 rows per block, shuffle-only.
// Lane handles 16 contiguous elems (= one quarter-head = 8 rope pairs).
// ---------------------------------------------------------------------------
__global__ __launch_bounds__(256) void norm_rope(
    bf16* __restrict__ q, bf16* __restrict__ k,
    const float* __restrict__ nqw, const float* __restrict__ nkw,
    const float* __restrict__ fcos, const float* __restrict__ fsin) {
  const int lane = threadIdx.x & 63, wave = threadIdx.x >> 6;
  const size_t row  = (size_t)blockIdx.x * 4 + wave;
  const size_t base = row * DIM_;
  const int e0 = lane * 16;
  const int j0 = (lane & 3) * 8;  // rope pair base within head

  float cs[8], sn[8];
#pragma unroll
  for (int i = 0; i < 8; ++i) {
    cs[i] = fcos[row * 32 + j0 + i];
    sn[i] = fsin[row * 32 + j0 + i];
  }

  // load both tensors up front for ILP
  bf16x8 qa = *(const bf16x8*)(q + base + e0);
  bf16x8 qb = *(const bf16x8*)(q + base + e0 + 8);
  bf16x8 ka = *(const bf16x8*)(k + base + e0);
  bf16x8 kb = *(const bf16x8*)(k + base + e0 + 8);

  float xq[16], xk[16];
#pragma unroll
  for (int i = 0; i < 8; ++i) {
    xq[i] = (float)qa[i]; xq[8 + i] = (float)qb[i];
    xk[i] = (float)ka[i]; xk[8 + i] = (float)kb[i];
  }
  float sq = 0.f, sk = 0.f;
#pragma unroll
  for (int i = 0; i < 16; ++i) { sq += xq[i] * xq[i]; sk += xk[i] * xk[i]; }
#pragma unroll
  for (int off = 32; off > 0; off >>= 1) {
    sq += __shfl_xor(sq, off);
    sk += __shfl_xor(sk, off);
  }
  const float rq = rsqrtf(sq * (1.0f / 1024.0f) + 1e-6f);
  const float rk = rsqrtf(sk * (1.0f / 1024.0f) + 1e-6f);
#pragma unroll
  for (int i = 0; i < 16; ++i) {
    xq[i] *= rq * nqw[e0 + i];
    xk[i] *= rk * nkw[e0 + i];
  }
  bf16x8 oa, ob, oc, od;
#pragma unroll
  for (int p = 0; p < 8; ++p) {
    const float c = cs[p], s = sn[p];
    const float q0 = xq[2 * p], q1 = xq[2 * p + 1];
    const float k0 = xk[2 * p], k1 = xk[2 * p + 1];
    const float qr = q0 * c - q1 * s, qi = q0 * s + q1 * c;
    const float kr = k0 * c - k1 * s, ki = k0 * s + k1 * c;
    if (p < 4) { oa[2 * p] = (bf16)qr; oa[2 * p + 1] = (bf16)qi;
                 oc[2 * p] = (bf16)kr; oc[2 * p + 1] = (bf16)ki; }
    else       { ob[2 * p - 8] = (bf16)qr; ob[2 * p - 7] = (bf16)qi;
                 od[2 * p - 8] = (bf16)kr; od[2 * p - 7] = (bf16)ki; }
  }
  *(bf16x8*)(q + base + e0)     = oa;
  *(bf16x8*)(q + base + e0 + 8) = ob;
  *(bf16x8*)(k + base + e0)     = oc;
  *(bf16x8*)(k + base + e0 + 8) = od;
}

// ---------------------------------------------------------------------------
// Windowed causal attention over frames (len 16, window 8), all heads per t.
// Block per t, 512 threads. k,v DMA'd to LDS; scores via MFMA 16x16x32;
// softmax on C-layout (row fq = quad*4+r, col fk = lane&15); PV reg-blocked.
// ---------------------------------------------------------------------------
__global__ __launch_bounds__(512, 4) void attn_win(
    const bf16* __restrict__ q, const bf16* __restrict__ k,
    const bf16* __restrict__ v, bf16* __restrict__ o) {
  __shared__ __align__(16) bf16 ks[16 * KROW];
  __shared__ __align__(16) bf16 vs[16 * KROW];
  __shared__ __align__(16) bf16 ps[16 * 256];  // [h][fq][fk]
  const int t    = blockIdx.x;
  const int tid  = threadIdx.x;
  const int wave = tid >> 6, lane = tid & 63;

  // ---- phase 1: DMA k,v (16 rows x 1024) into LDS, 2 half-row issues/row
#pragma unroll
  for (int i = 0; i < 4; ++i) {
    const int j = wave * 4 + i;  // 0..31
    const int r = j >> 1, half = j & 1;
    const size_t g = ((size_t)r * SEQ + t) * DIM_ + half * 512 + lane * 8;
    load_lds_16B(k + g, ks + r * KROW + half * 512);
    load_lds_16B(v + g, vs + r * KROW + half * 512);
  }
  __syncthreads();

  // ---- phase 2: scores + softmax; wave handles heads wave*2, wave*2+1
  const int fl  = lane & 15;         // fragment row/col index
  const int kq  = (lane >> 4) * 8;   // k-offset within fragment
#pragma unroll
  for (int hh = 0; hh < 2; ++hh) {
    const int h = wave * 2 + hh;
    const size_t qg = ((size_t)fl * SEQ + t) * DIM_ + h * HD_ + kq;
    bf16x8 aq0 = *(const bf16x8*)(q + qg);
    bf16x8 aq1 = *(const bf16x8*)(q + qg + 32);
    const int ko = fl * KROW + h * HD_ + kq;
    bf16x8 bk0 = *(const bf16x8*)(ks + ko);
    bf16x8 bk1 = *(const bf16x8*)(ks + ko + 32);
    f32x4 sc = {0.f, 0.f, 0.f, 0.f};
    sc = __builtin_amdgcn_mfma_f32_16x16x32_bf16(aq0, bk0, sc, 0, 0, 0);
    sc = __builtin_amdgcn_mfma_f32_16x16x32_bf16(aq1, bk1, sc, 0, 0, 0);
#pragma unroll
    for (int r = 0; r < 4; ++r) {
      const int row = (lane >> 4) * 4 + r;  // fq
      const bool valid = (fl <= row) && (row - fl < 8);
      float s = valid ? sc[r] * 0.125f : -1e30f;
      float m = s;
#pragma unroll
      for (int off = 8; off > 0; off >>= 1) m = fmaxf(m, __shfl_xor(m, off));
      const float e = __expf(s - m);
      float su = e;
#pragma unroll
      for (int off = 8; off > 0; off >>= 1) su += __shfl_xor(su, off);
      ps[h * 256 + row * 16 + fl] = (bf16)(e / su);
    }
  }
  __syncthreads();

  // ---- phase 3: PV, register-blocked. thread = (h, d-chunk, fq-group)
  const int h3 = tid >> 5;
  const int dc = (tid >> 2) & 7;
  const int fg = tid & 3;
  bf16x8 pr[8];  // probs rows fg*4..fg*4+3, 16 bf16 each
#pragma unroll
  for (int i = 0; i < 4; ++i) {
    pr[2 * i]     = *(const bf16x8*)(ps + h3 * 256 + (fg * 4 + i) * 16);
    pr[2 * i + 1] = *(const bf16x8*)(ps + h3 * 256 + (fg * 4 + i) * 16 + 8);
  }
  float acc[4][8];
#pragma unroll
  for (int i = 0; i < 4; ++i)
#pragma unroll
    for (int d = 0; d < 8; ++d) acc[i][d] = 0.f;

  const bf16* vb = vs + h3 * HD_ + dc * 8;
#pragma unroll
  for (int fk2 = 0; fk2 < 16; ++fk2) {
    bf16x8 vv8 = *(const bf16x8*)(vb + fk2 * KROW);
    float vf[8];
#pragma unroll
    for (int d = 0; d < 8; ++d) vf[d] = (float)vv8[d];
#pragma unroll
    for (int i = 0; i < 4; ++i) {
      const float pp = (float)((fk2 < 8) ? pr[2 * i][fk2] : pr[2 * i + 1][fk2 - 8]);
#pragma unroll
      for (int d = 0; d < 8; ++d) acc[i][d] += pp * vf[d];
    }
  }
#pragma unroll
  for (int i = 0; i < 4; ++i) {
    bf16x8 ov;
#pragma unroll
    for (int d = 0; d < 8; ++d) ov[d] = (bf16)acc[i][d];
    *(bf16x8*)(o + ((size_t)(fg * 4 + i) * SEQ + t) * DIM_ + h3 * HD_ + dc * 8) = ov;
  }
}

// ---------------------------------------------------------------------------
extern "C" void kernel_launch(void* const* d_in, const int* in_sizes, int n_in,
                              void* d_out, int out_size, void* d_ws,
                              size_t ws_size, hipStream_t stream) {
  const float* x    = (const float*)d_in[0];
  const float* fcos = (const float*)d_in[1];
  const float* fsin = (const float*)d_in[2];
  const float* q_w  = (const float*)d_in[3];
  const float* q_b  = (const float*)d_in[4];
  const float* k_w  = (const float*)d_in[5];
  const float* k_b  = (const float*)d_in[6];
  const float* v_w  = (const float*)d_in[7];
  const float* v_b  = (const float*)d_in[8];
  const float* o_w  = (const float*)d_in[9];
  const float* o_b  = (const float*)d_in[10];
  const float* nqw  = (const float*)d_in[11];
  const float* nkw  = (const float*)d_in[12];
  float* out = (float*)d_out;

  char* ws = (char*)d_ws;
  const size_t SZ  = (size_t)TOK * DIM_ * 2;
  const size_t WSZ = (size_t)DIM_ * DIM_ * 2;
  bf16* xb = (bf16*)(ws);
  bf16* wq = (bf16*)(ws + SZ);
  bf16* wk = (bf16*)(ws + SZ + WSZ);
  bf16* wv = (bf16*)(ws + SZ + 2 * WSZ);
  bf16* wo = (bf16*)(ws + SZ + 3 * WSZ);
  bf16* qq = (bf16*)(ws + SZ + 4 * WSZ);
  bf16* kk = (bf16*)(ws + SZ + 4 * WSZ + SZ);
  bf16* vv = (bf16*)(ws + SZ + 4 * WSZ + 2 * SZ);
  bf16* om = xb;  // x_bf16 dead after gemm_qkv; reuse for attention output

  const int NTOT = TOK * DIM_;
  const int NW   = DIM_ * DIM_;

  cvt_bf16<<<NTOT / 2048, 256, 0, stream>>>(x, xb, NTOT);
  cvt_w4<<<dim3(NW / 2048, 4), 256, 0, stream>>>(q_w, k_w, v_w, o_w,
                                                 wq, wk, wv, wo);

  dim3 gq(TOK / 128, DIM_ / 128, 3);
  gemm_qkv<<<gq, 256, 0, stream>>>(xb, wq, wk, wv, q_b, k_b, v_b, qq, kk, vv);

  norm_rope<<<TOK / 4, 256, 0, stream>>>(qq, kk, nqw, nkw, fcos, fsin);

  attn_win<<<SEQ, 512, 0, stream>>>(qq, kk, vv, om);

  gemm_out<<<dim3(TOK / 128, DIM_ / 128), 256, 0, stream>>>(om, wo, o_b, out);
}

// Round 3
// 558.757 us; speedup vs baseline: 1.2183x; 1.2183x over previous
//
#include <hip/hip_runtime.h>
#include <hip/hip_bf16.h>
#include <math.h>

typedef __bf16 bf16;
typedef bf16 bf16x8 __attribute__((ext_vector_type(8)));
typedef bf16 bf16x4 __attribute__((ext_vector_type(4)));
typedef float f32x4 __attribute__((ext_vector_type(4)));

#define NFRM 16
#define SEQ  1472
#define TOK  (NFRM * SEQ)   /* 23552 */
#define DIM_ 1024
#define NH_  16
#define HD_  64
#define KROW 1032           /* LDS row stride (bf16) for k/v: 1024 + 8 pad */

// Internal q/k/v/attn-out layout is T-MAJOR: row' = t*16 + f  (one t's 16
// frames contiguous, 32KB). GEMMs permute on the A-load side only.

__device__ __forceinline__ void load_lds_16B(const void* g, void* l) {
  __builtin_amdgcn_global_load_lds(
      (const __attribute__((address_space(1))) unsigned int*)g,
      (__attribute__((address_space(3))) unsigned int*)l,
      16, 0, 0);
}

// ---------------------------------------------------------------------------
__global__ __launch_bounds__(256) void cvt_bf16(const float* __restrict__ s,
                                                bf16* __restrict__ d, int n) {
  size_t i = ((size_t)blockIdx.x * 256 + threadIdx.x) * 8;
  if (i >= (size_t)n) return;
  f32x4 a = *(const f32x4*)(s + i);
  f32x4 b = *(const f32x4*)(s + i + 4);
  bf16x8 o;
  o[0] = (bf16)a[0]; o[1] = (bf16)a[1]; o[2] = (bf16)a[2]; o[3] = (bf16)a[3];
  o[4] = (bf16)b[0]; o[5] = (bf16)b[1]; o[6] = (bf16)b[2]; o[7] = (bf16)b[3];
  *(bf16x8*)(d + i) = o;
}

__global__ __launch_bounds__(256) void cvt_w4(
    const float* __restrict__ w0, const float* __restrict__ w1,
    const float* __restrict__ w2, const float* __restrict__ w3,
    bf16* __restrict__ d0, bf16* __restrict__ d1,
    bf16* __restrict__ d2, bf16* __restrict__ d3) {
  const int z = blockIdx.y;
  const float* s = (z == 0) ? w0 : (z == 1) ? w1 : (z == 2) ? w2 : w3;
  bf16* d       = (z == 0) ? d0 : (z == 1) ? d1 : (z == 2) ? d2 : d3;
  size_t i = ((size_t)blockIdx.x * 256 + threadIdx.x) * 8;
  f32x4 a = *(const f32x4*)(s + i);
  f32x4 b = *(const f32x4*)(s + i + 4);
  bf16x8 o;
  o[0] = (bf16)a[0]; o[1] = (bf16)a[1]; o[2] = (bf16)a[2]; o[3] = (bf16)a[3];
  o[4] = (bf16)b[0]; o[5] = (bf16)b[1]; o[6] = (bf16)b[2]; o[7] = (bf16)b[3];
  *(bf16x8*)(d + i) = o;
}

// ---------------------------------------------------------------------------
// m97-structure GEMM with A-row permutation (AMAP 0: identity,
// 1: C row' = t*16+f reads A row f*SEQ+t,  2: C row f*SEQ+t reads A row t*16+f)
// ---------------------------------------------------------------------------
template <typename OutT, int AMAP>
__device__ __forceinline__ void gemm_body(const bf16* __restrict__ A,
                                          const bf16* __restrict__ B,
                                          const float* __restrict__ bias,
                                          OutT* __restrict__ C,
                                          bf16* As, bf16* Bs) {
  const int tid  = threadIdx.x;
  const int wave = tid >> 6;
  const int lane = tid & 63;
  const size_t am0 = (size_t)blockIdx.x * 128;
  const size_t bn0 = (size_t)blockIdx.y * 128;

  f32x4 acc[4][4];
#pragma unroll
  for (int i = 0; i < 4; ++i)
#pragma unroll
    for (int j = 0; j < 4; ++j) {
      f32x4 z = {0.f, 0.f, 0.f, 0.f};
      acc[i][j] = z;
    }

  const int wm   = (wave >> 1) * 64;
  const int wn   = (wave & 1) * 64;
  const int frow = lane & 15;
  const int fko  = (lane >> 4) * 8;

  // per-lane staging addresses, hoisted out of the K-loop
  const int r0 = (wave * 64 + lane) >> 2;  // 0..63
  const int kc = (lane & 3) * 8;
  size_t ar0 = am0 + r0, ar1 = am0 + r0 + 64;
  if (AMAP == 1) {          // out row' = t*16+f  ->  A row = f*SEQ+t
    ar0 = (ar0 & 15) * (size_t)SEQ + (ar0 >> 4);
    ar1 = (ar1 & 15) * (size_t)SEQ + (ar1 >> 4);
  } else if (AMAP == 2) {   // out row = f*SEQ+t  ->  A row' = t*16+f
    const unsigned f0 = (unsigned)ar0 / SEQ, f1 = (unsigned)ar1 / SEQ;
    ar0 = ((unsigned)ar0 - f0 * SEQ) * 16ull + f0;
    ar1 = ((unsigned)ar1 - f1 * SEQ) * 16ull + f1;
  }
  const bf16* pa0 = A + ar0 * DIM_ + kc;
  const bf16* pa1 = A + ar1 * DIM_ + kc;
  const bf16* pb0 = B + (bn0 + r0) * DIM_ + kc;
  const bf16* pb1 = B + (bn0 + r0 + 64) * DIM_ + kc;
  const int cb0 = wave * 64, cb1 = 256 + wave * 64;

  for (int k0 = 0; k0 < DIM_; k0 += 32) {
    load_lds_16B(pa0 + k0, As + cb0 * 8);
    load_lds_16B(pb0 + k0, Bs + cb0 * 8);
    load_lds_16B(pa1 + k0, As + cb1 * 8);
    load_lds_16B(pb1 + k0, Bs + cb1 * 8);
    __syncthreads();
    bf16x8 af[4], bfv[4];
#pragma unroll
    for (int i = 0; i < 4; ++i)
      af[i] = *(const bf16x8*)(As + (wm + i * 16 + frow) * 32 + fko);
#pragma unroll
    for (int j = 0; j < 4; ++j)
      bfv[j] = *(const bf16x8*)(Bs + (wn + j * 16 + frow) * 32 + fko);
#pragma unroll
    for (int i = 0; i < 4; ++i)
#pragma unroll
      for (int j = 0; j < 4; ++j)
        acc[i][j] = __builtin_amdgcn_mfma_f32_16x16x32_bf16(af[i], bfv[j],
                                                            acc[i][j], 0, 0, 0);
    __syncthreads();
  }

  const int cl = lane & 15;
  const int rq = (lane >> 4) * 4;
#pragma unroll
  for (int i = 0; i < 4; ++i)
#pragma unroll
    for (int j = 0; j < 4; ++j) {
      const int nc   = (int)bn0 + wn + j * 16 + cl;
      const float bb = bias[nc];
#pragma unroll
      for (int r = 0; r < 4; ++r) {
        const size_t mr = am0 + wm + i * 16 + rq + r;
        C[mr * DIM_ + nc] = (OutT)(acc[i][j][r] + bb);
      }
    }
}

__global__ __launch_bounds__(256) void gemm_qkv(
    const bf16* __restrict__ A,
    const bf16* __restrict__ Bq, const bf16* __restrict__ Bk,
    const bf16* __restrict__ Bv,
    const float* __restrict__ bq, const float* __restrict__ bk,
    const float* __restrict__ bv,
    bf16* __restrict__ Cq, bf16* __restrict__ Ck, bf16* __restrict__ Cv) {
  __shared__ __align__(16) bf16 As[128 * 32];
  __shared__ __align__(16) bf16 Bs[128 * 32];
  const int z = blockIdx.z;
  const bf16* B    = (z == 0) ? Bq : (z == 1) ? Bk : Bv;
  const float* bia = (z == 0) ? bq : (z == 1) ? bk : bv;
  bf16* C          = (z == 0) ? Cq : (z == 1) ? Ck : Cv;
  gemm_body<bf16, 1>(A, B, bia, C, As, Bs);
}

__global__ __launch_bounds__(256) void gemm_out(
    const bf16* __restrict__ A, const bf16* __restrict__ B,
    const float* __restrict__ bias, float* __restrict__ C) {
  __shared__ __align__(16) bf16 As[128 * 32];
  __shared__ __align__(16) bf16 Bs[128 * 32];
  gemm_body<float, 2>(A, B, bias, C, As, Bs);
}

// ---------------------------------------------------------------------------
// In-place RMSNorm + RoPE on t-major rows. Wave per row, 4 rows per block.
// ---------------------------------------------------------------------------
__global__ __launch_bounds__(256) void norm_rope(
    bf16* __restrict__ q, bf16* __restrict__ k,
    const float* __restrict__ nqw, const float* __restrict__ nkw,
    const float* __restrict__ fcos, const float* __restrict__ fsin) {
  const int lane = threadIdx.x & 63, wave = threadIdx.x >> 6;
  const size_t row  = (size_t)blockIdx.x * 4 + wave;   // t-major row'
  const size_t base = row * DIM_;
  const size_t pos  = (row & 15) * (size_t)SEQ + (row >> 4);  // f*SEQ + t
  const int e0 = lane * 16;
  const int j0 = (lane & 3) * 8;

  float cs[8], sn[8];
#pragma unroll
  for (int i = 0; i < 8; ++i) {
    cs[i] = fcos[pos * 32 + j0 + i];
    sn[i] = fsin[pos * 32 + j0 + i];
  }

  bf16x8 qa = *(const bf16x8*)(q + base + e0);
  bf16x8 qb = *(const bf16x8*)(q + base + e0 + 8);
  bf16x8 ka = *(const bf16x8*)(k + base + e0);
  bf16x8 kb = *(const bf16x8*)(k + base + e0 + 8);

  float xq[16], xk[16];
#pragma unroll
  for (int i = 0; i < 8; ++i) {
    xq[i] = (float)qa[i]; xq[8 + i] = (float)qb[i];
    xk[i] = (float)ka[i]; xk[8 + i] = (float)kb[i];
  }
  float sq = 0.f, sk = 0.f;
#pragma unroll
  for (int i = 0; i < 16; ++i) { sq += xq[i] * xq[i]; sk += xk[i] * xk[i]; }
#pragma unroll
  for (int off = 32; off > 0; off >>= 1) {
    sq += __shfl_xor(sq, off);
    sk += __shfl_xor(sk, off);
  }
  const float rq = rsqrtf(sq * (1.0f / 1024.0f) + 1e-6f);
  const float rk = rsqrtf(sk * (1.0f / 1024.0f) + 1e-6f);
#pragma unroll
  for (int i = 0; i < 16; ++i) {
    xq[i] *= rq * nqw[e0 + i];
    xk[i] *= rk * nkw[e0 + i];
  }
  bf16x8 oa, ob, oc, od;
#pragma unroll
  for (int p = 0; p < 8; ++p) {
    const float c = cs[p], s = sn[p];
    const float q0 = xq[2 * p], q1 = xq[2 * p + 1];
    const float k0 = xk[2 * p], k1 = xk[2 * p + 1];
    const float qr = q0 * c - q1 * s, qi = q0 * s + q1 * c;
    const float kr = k0 * c - k1 * s, ki = k0 * s + k1 * c;
    if (p < 4) { oa[2 * p] = (bf16)qr; oa[2 * p + 1] = (bf16)qi;
                 oc[2 * p] = (bf16)kr; oc[2 * p + 1] = (bf16)ki; }
    else       { ob[2 * p - 8] = (bf16)qr; ob[2 * p - 7] = (bf16)qi;
                 od[2 * p - 8] = (bf16)kr; od[2 * p - 7] = (bf16)ki; }
  }
  *(bf16x8*)(q + base + e0)     = oa;
  *(bf16x8*)(q + base + e0 + 8) = ob;
  *(bf16x8*)(k + base + e0)     = oc;
  *(bf16x8*)(k + base + e0 + 8) = od;
}

// ---------------------------------------------------------------------------
// Windowed attention, t-major layout: block per t, all data in one 32KB slab.
// ---------------------------------------------------------------------------
__global__ __launch_bounds__(512, 4) void attn_win(
    const bf16* __restrict__ q, const bf16* __restrict__ k,
    const bf16* __restrict__ v, bf16* __restrict__ o) {
  __shared__ __align__(16) bf16 ks[16 * KROW];
  __shared__ __align__(16) bf16 vs[16 * KROW];
  __shared__ __align__(16) bf16 ps[16 * 256];  // [h][fq][fk]
  const int t    = blockIdx.x;
  const int tid  = threadIdx.x;
  const int wave = tid >> 6, lane = tid & 63;
  const size_t tb = (size_t)t * (16 * DIM_);   // base elem of t's slab

  // phase 1: stream k,v (2 x 32KB contiguous) into LDS
#pragma unroll
  for (int i = 0; i < 4; ++i) {
    const int j = wave * 4 + i;  // 0..31
    const int r = j >> 1, half = j & 1;
    const size_t g = tb + (size_t)r * DIM_ + half * 512 + lane * 8;
    load_lds_16B(k + g, ks + r * KROW + half * 512);
    load_lds_16B(v + g, vs + r * KROW + half * 512);
  }
  __syncthreads();

  // phase 2: scores via MFMA + softmax; wave handles heads wave*2, wave*2+1
  const int fl  = lane & 15;
  const int kq  = (lane >> 4) * 8;
#pragma unroll
  for (int hh = 0; hh < 2; ++hh) {
    const int h = wave * 2 + hh;
    const size_t qg = tb + (size_t)fl * DIM_ + h * HD_ + kq;
    bf16x8 aq0 = *(const bf16x8*)(q + qg);
    bf16x8 aq1 = *(const bf16x8*)(q + qg + 32);
    const int ko = fl * KROW + h * HD_ + kq;
    bf16x8 bk0 = *(const bf16x8*)(ks + ko);
    bf16x8 bk1 = *(const bf16x8*)(ks + ko + 32);
    f32x4 sc = {0.f, 0.f, 0.f, 0.f};
    sc = __builtin_amdgcn_mfma_f32_16x16x32_bf16(aq0, bk0, sc, 0, 0, 0);
    sc = __builtin_amdgcn_mfma_f32_16x16x32_bf16(aq1, bk1, sc, 0, 0, 0);
#pragma unroll
    for (int r = 0; r < 4; ++r) {
      const int row = (lane >> 4) * 4 + r;  // fq
      const bool valid = (fl <= row) && (row - fl < 8);
      float s = valid ? sc[r] * 0.125f : -1e30f;
      float m = s;
#pragma unroll
      for (int off = 8; off > 0; off >>= 1) m = fmaxf(m, __shfl_xor(m, off));
      const float e = __expf(s - m);
      float su = e;
#pragma unroll
      for (int off = 8; off > 0; off >>= 1) su += __shfl_xor(su, off);
      ps[h * 256 + row * 16 + fl] = (bf16)(e / su);
    }
  }
  __syncthreads();

  // phase 3: PV, register-blocked. thread = (h, d-chunk, fq-group)
  const int h3 = tid >> 5;
  const int dc = (tid >> 2) & 7;
  const int fg = tid & 3;
  bf16x8 pr[8];
#pragma unroll
  for (int i = 0; i < 4; ++i) {
    pr[2 * i]     = *(const bf16x8*)(ps + h3 * 256 + (fg * 4 + i) * 16);
    pr[2 * i + 1] = *(const bf16x8*)(ps + h3 * 256 + (fg * 4 + i) * 16 + 8);
  }
  float acc[4][8];
#pragma unroll
  for (int i = 0; i < 4; ++i)
#pragma unroll
    for (int d = 0; d < 8; ++d) acc[i][d] = 0.f;

  const bf16* vb = vs + h3 * HD_ + dc * 8;
#pragma unroll
  for (int fk2 = 0; fk2 < 16; ++fk2) {
    bf16x8 vv8 = *(const bf16x8*)(vb + fk2 * KROW);
    float vf[8];
#pragma unroll
    for (int d = 0; d < 8; ++d) vf[d] = (float)vv8[d];
#pragma unroll
    for (int i = 0; i < 4; ++i) {
      const float pp = (float)((fk2 < 8) ? pr[2 * i][fk2] : pr[2 * i + 1][fk2 - 8]);
#pragma unroll
      for (int d = 0; d < 8; ++d) acc[i][d] += pp * vf[d];
    }
  }
#pragma unroll
  for (int i = 0; i < 4; ++i) {
    bf16x8 ov;
#pragma unroll
    for (int d = 0; d < 8; ++d) ov[d] = (bf16)acc[i][d];
    *(bf16x8*)(o + tb + (size_t)(fg * 4 + i) * DIM_ + h3 * HD_ + dc * 8) = ov;
  }
}

// ---------------------------------------------------------------------------
extern "C" void kernel_launch(void* const* d_in, const int* in_sizes, int n_in,
                              void* d_out, int out_size, void* d_ws,
                              size_t ws_size, hipStream_t stream) {
  const float* x    = (const float*)d_in[0];
  const float* fcos = (const float*)d_in[1];
  const float* fsin = (const float*)d_in[2];
  const float* q_w  = (const float*)d_in[3];
  const float* q_b  = (const float*)d_in[4];
  const float* k_w  = (const float*)d_in[5];
  const float* k_b  = (const float*)d_in[6];
  const float* v_w  = (const float*)d_in[7];
  const float* v_b  = (const float*)d_in[8];
  const float* o_w  = (const float*)d_in[9];
  const float* o_b  = (const float*)d_in[10];
  const float* nqw  = (const float*)d_in[11];
  const float* nkw  = (const float*)d_in[12];
  float* out = (float*)d_out;

  char* ws = (char*)d_ws;
  const size_t SZ  = (size_t)TOK * DIM_ * 2;
  const size_t WSZ = (size_t)DIM_ * DIM_ * 2;
  bf16* xb = (bf16*)(ws);
  bf16* wq = (bf16*)(ws + SZ);
  bf16* wk = (bf16*)(ws + SZ + WSZ);
  bf16* wv = (bf16*)(ws + SZ + 2 * WSZ);
  bf16* wo = (bf16*)(ws + SZ + 3 * WSZ);
  bf16* qq = (bf16*)(ws + SZ + 4 * WSZ);
  bf16* kk = (bf16*)(ws + SZ + 4 * WSZ + SZ);
  bf16* vv = (bf16*)(ws + SZ + 4 * WSZ + 2 * SZ);
  bf16* om = xb;  // x_bf16 dead after gemm_qkv; reuse for attention output

  const int NTOT = TOK * DIM_;
  const int NW   = DIM_ * DIM_;

  cvt_bf16<<<NTOT / 2048, 256, 0, stream>>>(x, xb, NTOT);
  cvt_w4<<<dim3(NW / 2048, 4), 256, 0, stream>>>(q_w, k_w, v_w, o_w,
                                                 wq, wk, wv, wo);

  dim3 gq(TOK / 128, DIM_ / 128, 3);
  gemm_qkv<<<gq, 256, 0, stream>>>(xb, wq, wk, wv, q_b, k_b, v_b, qq, kk, vv);

  norm_rope<<<TOK / 4, 256, 0, stream>>>(qq, kk, nqw, nkw, fcos, fsin);

  attn_win<<<SEQ, 512, 0, stream>>>(qq, kk, vv, om);

  gemm_out<<<dim3(TOK / 128, DIM_ / 128), 256, 0, stream>>>(om, wo, o_b, out);
}